// Round 4
// baseline (410.923 us; speedup 1.0000x reference)
//
#include <hip/hip_runtime.h>
#include <hip/hip_bf16.h>
#include <math.h>

#define B_SZ 512
#define C_SZ 100000
#define D_SZ 512

#define BM 128
#define BN 128
#define NTILES 782   // ceil(100000/128)
#define MTILES 8     // 1024 / 128
#define NBLK (NTILES * MTILES)

typedef __attribute__((ext_vector_type(8))) short bf16x8;
typedef __attribute__((ext_vector_type(4))) float f32x4;

__device__ __forceinline__ unsigned short bf16r(float x) {
  union { float f; unsigned int u; } c; c.f = x;
  unsigned int r = (c.u + 0x7FFFu + ((c.u >> 16) & 1u)) >> 16;
  return (unsigned short)r;
}

__device__ __forceinline__ float bf2f(unsigned short u) {
  union { unsigned int u; float f; } c; c.u = ((unsigned int)u) << 16;
  return c.f;
}

// ---------------- kernel 1: normalize weight rows -> bf16 ----------------
__global__ __launch_bounds__(256) void k_norm_w(const float* __restrict__ w,
                                                __hip_bfloat16* __restrict__ wn) {
  const int row = blockIdx.x * 4 + (threadIdx.x >> 6);
  const int lane = threadIdx.x & 63;
  const float4* wr = (const float4*)(w + (size_t)row * D_SZ);
  float4 v0 = wr[lane];
  float4 v1 = wr[64 + lane];
  float ss = v0.x*v0.x + v0.y*v0.y + v0.z*v0.z + v0.w*v0.w
           + v1.x*v1.x + v1.y*v1.y + v1.z*v1.z + v1.w*v1.w;
  #pragma unroll
  for (int o = 32; o; o >>= 1) ss += __shfl_xor(ss, o, 64);
  const float rn = __builtin_amdgcn_rsqf(fmaxf(ss, 1e-24f));
  ushort4 u0, u1;
  u0.x = bf16r(v0.x * rn); u0.y = bf16r(v0.y * rn);
  u0.z = bf16r(v0.z * rn); u0.w = bf16r(v0.w * rn);
  u1.x = bf16r(v1.x * rn); u1.y = bf16r(v1.y * rn);
  u1.z = bf16r(v1.z * rn); u1.w = bf16r(v1.w * rn);
  ushort4* out = (ushort4*)(wn + (size_t)row * D_SZ);
  out[lane] = u0;
  out[64 + lane] = u1;
}

// ------- kernel 2: normalize embeddings, gather w_y, per-row params -------
// A layout: row 2b = e_hat[b] (bf16), row 2b+1 = w_hat[label[b]] (bf16)
__global__ __launch_bounds__(64) void k_prep(const float* __restrict__ e,
                                             const int* __restrict__ labels,
                                             const __hip_bfloat16* __restrict__ wn,
                                             __hip_bfloat16* __restrict__ A,
                                             float4* __restrict__ params) {
  const int b = blockIdx.x;
  const int lane = threadIdx.x;
  const float4* er = (const float4*)(e + (size_t)b * D_SZ);
  float4 v0 = er[lane], v1 = er[64 + lane];
  float ss = v0.x*v0.x + v0.y*v0.y + v0.z*v0.z + v0.w*v0.w
           + v1.x*v1.x + v1.y*v1.y + v1.z*v1.z + v1.w*v1.w;
  #pragma unroll
  for (int o = 32; o; o >>= 1) ss += __shfl_xor(ss, o, 64);
  const float rn = __builtin_amdgcn_rsqf(fmaxf(ss, 1e-24f));
  v0.x *= rn; v0.y *= rn; v0.z *= rn; v0.w *= rn;
  v1.x *= rn; v1.y *= rn; v1.z *= rn; v1.w *= rn;

  ushort4 u0, u1;
  u0.x = bf16r(v0.x); u0.y = bf16r(v0.y); u0.z = bf16r(v0.z); u0.w = bf16r(v0.w);
  u1.x = bf16r(v1.x); u1.y = bf16r(v1.y); u1.z = bf16r(v1.z); u1.w = bf16r(v1.w);
  ushort4* arow_e = (ushort4*)(A + (size_t)(2 * b) * D_SZ);
  arow_e[lane] = u0;
  arow_e[64 + lane] = u1;

  const int lab = labels[b];
  const ushort4* wr = (const ushort4*)(wn + (size_t)lab * D_SZ);
  ushort4 w0 = wr[lane], w1 = wr[64 + lane];
  ushort4* arow_w = (ushort4*)(A + (size_t)(2 * b + 1) * D_SZ);
  arow_w[lane] = w0;
  arow_w[64 + lane] = w1;

  float d = v0.x*bf2f(w0.x) + v0.y*bf2f(w0.y) + v0.z*bf2f(w0.z) + v0.w*bf2f(w0.w)
          + v1.x*bf2f(w1.x) + v1.y*bf2f(w1.y) + v1.z*bf2f(w1.z) + v1.w*bf2f(w1.w);
  #pragma unroll
  for (int o = 32; o; o >>= 1) d += __shfl_xor(d, o, 64);

  if (lane == 0) {
    const float cos_m = 0.877582561890372716f;  // cos(0.5)
    const float sin_m = 0.479425538604203000f;  // sin(0.5)
    float cos_t = fminf(fmaxf(d, -1.0f), 1.0f);
    float sin_t = sqrtf(fmaxf(1.0f - cos_t * cos_t, 0.0f));
    float cos_tm = cos_t * cos_m - sin_t * sin_m;
    float sin_tm = sin_t * cos_m + cos_t * sin_m;
    float inv_st = 1.0f / fmaxf(sin_t, 1e-20f);
    params[b] = make_float4(cos_tm, sin_m * inv_st, sin_tm * inv_st, 0.0f);
  }
}

// -------- kernel 3: register-direct GEMM (no LDS staging) + epilogue --------
// B (wn) is L2-resident per XCD thanks to the chunked remap; LDS staging was
// pure overhead (barrier drains). Load MFMA fragments straight from L2.
__device__ __forceinline__ float termf(float de, float dwy, float4 p, bool kill) {
  float c = fminf(fmaxf(de, -1.0f), 1.0f);
  float s = p.z * dwy - p.y * de;            // (sin_tm*dwy - sin_m*de)/sin_t
  float x = fmaxf(fmaf(-2.0f, s, 2.0f), 1e-20f);
  float t = (c - p.x) * __builtin_amdgcn_rsqf(x);
  float r = __expf(t);
  return kill ? 0.0f : r;
}

__global__ __launch_bounds__(256) void k_gemm(const __hip_bfloat16* __restrict__ A,
                                              const __hip_bfloat16* __restrict__ Wn,
                                              const float4* __restrict__ params,
                                              const int* __restrict__ labels,
                                              float* __restrict__ part) {
  __shared__ float ered[64];
  __shared__ float4 pl[64];
  __shared__ int ll[64];

  const int bid = blockIdx.x;
  const int p = (bid & 7) * NTILES + (bid >> 3);  // XCD-chunked remap
  const int nt = p >> 3, mt = p & 7;
  const int t = threadIdx.x;
  const int w = t >> 6, l = t & 63;
  const int m0 = mt * BM;
  const int n0 = nt * BN;
  const int b0 = mt * 64;

  if (t < 64) {
    ered[t] = 0.0f;
    pl[t] = params[b0 + t];
    ll[t] = labels[b0 + t];
  }

  const int wm = (w >> 1) * 64;
  const int wn_ = (w & 1) * 64;
  const int r16 = l & 15;
  const int g = l >> 4;

  // Per-lane fragment base offsets (elements). A-frag for 16x16x32 bf16:
  // lane l holds row (l&15), k = (l>>4)*8 .. +7  => offset row*D + g*8.
  int aoff[4][2], boff[4][2];
  #pragma unroll
  for (int mf = 0; mf < 4; ++mf) {
    int row = m0 + wm + mf * 16 + r16;
    #pragma unroll
    for (int kki = 0; kki < 2; ++kki)
      aoff[mf][kki] = row * D_SZ + (kki * 4 + g) * 8;
  }
  #pragma unroll
  for (int nf = 0; nf < 4; ++nf) {
    int j = n0 + wn_ + nf * 16 + r16;
    if (j >= C_SZ) j = C_SZ - 1;     // clamp; masked in epilogue
    #pragma unroll
    for (int kki = 0; kki < 2; ++kki)
      boff[nf][kki] = j * D_SZ + (kki * 4 + g) * 8;
  }

  f32x4 acc[4][4] = {};

  #pragma unroll
  for (int k0 = 0; k0 < D_SZ; k0 += 64) {
    bf16x8 af[4][2], bfr[4][2];
    #pragma unroll
    for (int mf = 0; mf < 4; ++mf)
      #pragma unroll
      for (int kki = 0; kki < 2; ++kki)
        af[mf][kki] = *(const bf16x8*)(A + aoff[mf][kki] + k0);
    #pragma unroll
    for (int nf = 0; nf < 4; ++nf)
      #pragma unroll
      for (int kki = 0; kki < 2; ++kki)
        bfr[nf][kki] = *(const bf16x8*)(Wn + (size_t)boff[nf][kki] + k0);
    #pragma unroll
    for (int kki = 0; kki < 2; ++kki)
      #pragma unroll
      for (int mf = 0; mf < 4; ++mf)
        #pragma unroll
        for (int nf = 0; nf < 4; ++nf)
          acc[mf][nf] = __builtin_amdgcn_mfma_f32_16x16x32_bf16(
              af[mf][kki], bfr[nf][kki], acc[mf][nf], 0, 0, 0);
  }

  __syncthreads();   // pl/ll/ered ready (first barrier since kernel start)

  // Epilogue: rows 2b (dot_e) and 2b+1 (dot_wy) are adjacent accumulator regs.
  #pragma unroll
  for (int mf = 0; mf < 4; ++mf) {
    int rloc = wm + mf * 16 + 4 * g;   // local A-row (even)
    int lb = rloc >> 1;                // local batch index (pair lb, lb+1)
    float4 p0 = pl[lb], p1 = pl[lb + 1];
    int lab0 = ll[lb], lab1 = ll[lb + 1];
    float s0 = 0.0f, s1 = 0.0f;
    #pragma unroll
    for (int nf = 0; nf < 4; ++nf) {
      int j = n0 + wn_ + nf * 16 + r16;
      bool oob = (j >= C_SZ);
      f32x4 c = acc[mf][nf];
      s0 += termf(c[0], c[1], p0, oob || (j == lab0));
      s1 += termf(c[2], c[3], p1, oob || (j == lab1));
    }
    // sum across the 16-lane r16 group (same lb), then one atomic
    #pragma unroll
    for (int o = 1; o < 16; o <<= 1) {
      s0 += __shfl_xor(s0, o, 64);
      s1 += __shfl_xor(s1, o, 64);
    }
    if (r16 == 0) {
      atomicAdd(&ered[lb], s0);
      atomicAdd(&ered[lb + 1], s1);
    }
  }
  __syncthreads();
  if (t < 64) part[(size_t)(b0 + t) * NTILES + nt] = ered[t];
}

// ---------------- kernel 4a: per-batch row sum + log1p ----------------
__global__ __launch_bounds__(256) void k_rowsum(const float* __restrict__ part,
                                                float* __restrict__ rowsum) {
  const int b = blockIdx.x;
  float s = 0.0f;
  for (int i = threadIdx.x; i < NTILES; i += 256) s += part[(size_t)b * NTILES + i];
  #pragma unroll
  for (int o = 32; o; o >>= 1) s += __shfl_xor(s, o, 64);
  __shared__ float red[4];
  if ((threadIdx.x & 63) == 0) red[threadIdx.x >> 6] = s;
  __syncthreads();
  if (threadIdx.x == 0)
    rowsum[b] = log1pf(red[0] + red[1] + red[2] + red[3]);
}

// ---------------- kernel 4b: final mean ----------------
__global__ __launch_bounds__(512) void k_final(const float* __restrict__ rowsum,
                                               float* __restrict__ out) {
  const int b = threadIdx.x;
  float v = rowsum[b];
  __shared__ float red[512];
  red[b] = v;
  __syncthreads();
  #pragma unroll
  for (int o = 256; o; o >>= 1) {
    if (b < o) red[b] += red[b + o];
    __syncthreads();
  }
  if (b == 0) out[0] = red[0] / (float)B_SZ;
}

extern "C" void kernel_launch(void* const* d_in, const int* in_sizes, int n_in,
                              void* d_out, int out_size, void* d_ws, size_t ws_size,
                              hipStream_t stream) {
  const float* emb = (const float*)d_in[0];
  const int* labels = (const int*)d_in[1];
  const float* w = (const float*)d_in[2];

  char* ws = (char*)d_ws;
  __hip_bfloat16* wn = (__hip_bfloat16*)ws;                       // 100000*512*2 B
  size_t off = (size_t)C_SZ * D_SZ * 2;
  __hip_bfloat16* Abuf = (__hip_bfloat16*)(ws + off);             // 1024*512*2 B
  off += (size_t)2 * B_SZ * D_SZ * 2;
  float4* params = (float4*)(ws + off);                           // 512*16 B
  off += (size_t)B_SZ * 16;
  float* part = (float*)(ws + off);                               // 512*782*4 B
  off += (size_t)B_SZ * NTILES * 4;
  float* rowsum = (float*)(ws + off);                             // 512*4 B
  off += (size_t)B_SZ * 4;

  k_norm_w<<<dim3(C_SZ / 4), dim3(256), 0, stream>>>(w, wn);
  k_prep<<<dim3(B_SZ), dim3(64), 0, stream>>>(emb, labels, wn, Abuf, params);
  k_gemm<<<dim3(NBLK), dim3(256), 0, stream>>>(Abuf, wn, params, labels, part);
  k_rowsum<<<dim3(B_SZ), dim3(256), 0, stream>>>(part, rowsum);
  k_final<<<dim3(1), dim3(512), 0, stream>>>(rowsum, (float*)d_out);
}

// Round 5
// 261.018 us; speedup vs baseline: 1.5743x; 1.5743x over previous
//
#include <hip/hip_runtime.h>
#include <hip/hip_bf16.h>
#include <math.h>

#define B_SZ 512
#define C_SZ 100000
#define D_SZ 512

#define BM 128
#define BN 128
#define BK 64
#define NTILES 782   // ceil(100000/128)
#define MTILES 8     // 1024 / 128
#define NBLK (NTILES * MTILES)
#define KSTEPS 8     // 512 / 64

typedef __attribute__((ext_vector_type(8))) short bf16x8;
typedef __attribute__((ext_vector_type(4))) float f32x4;

__device__ __forceinline__ void gload_lds16(const void* gptr, void* lptr) {
  __builtin_amdgcn_global_load_lds(
      (const __attribute__((address_space(1))) void*)gptr,
      (__attribute__((address_space(3))) void*)lptr,
      16, 0, 0);
}

__device__ __forceinline__ unsigned short bf16r(float x) {
  union { float f; unsigned int u; } c; c.f = x;
  unsigned int r = (c.u + 0x7FFFu + ((c.u >> 16) & 1u)) >> 16;
  return (unsigned short)r;
}

__device__ __forceinline__ float bf2f(unsigned short u) {
  union { unsigned int u; float f; } c; c.u = ((unsigned int)u) << 16;
  return c.f;
}

// ---------------- kernel 1: normalize weight rows -> bf16 ----------------
__global__ __launch_bounds__(256) void k_norm_w(const float* __restrict__ w,
                                                __hip_bfloat16* __restrict__ wn) {
  const int row = blockIdx.x * 4 + (threadIdx.x >> 6);
  const int lane = threadIdx.x & 63;
  const float4* wr = (const float4*)(w + (size_t)row * D_SZ);
  float4 v0 = wr[lane];
  float4 v1 = wr[64 + lane];
  float ss = v0.x*v0.x + v0.y*v0.y + v0.z*v0.z + v0.w*v0.w
           + v1.x*v1.x + v1.y*v1.y + v1.z*v1.z + v1.w*v1.w;
  #pragma unroll
  for (int o = 32; o; o >>= 1) ss += __shfl_xor(ss, o, 64);
  const float rn = __builtin_amdgcn_rsqf(fmaxf(ss, 1e-24f));
  ushort4 u0, u1;
  u0.x = bf16r(v0.x * rn); u0.y = bf16r(v0.y * rn);
  u0.z = bf16r(v0.z * rn); u0.w = bf16r(v0.w * rn);
  u1.x = bf16r(v1.x * rn); u1.y = bf16r(v1.y * rn);
  u1.z = bf16r(v1.z * rn); u1.w = bf16r(v1.w * rn);
  ushort4* out = (ushort4*)(wn + (size_t)row * D_SZ);
  out[lane] = u0;
  out[64 + lane] = u1;
}

// ------- kernel 2: normalize embeddings, gather w_y, per-row params -------
// A layout: row 2b = e_hat[b] (bf16), row 2b+1 = w_hat[label[b]] (bf16)
__global__ __launch_bounds__(64) void k_prep(const float* __restrict__ e,
                                             const int* __restrict__ labels,
                                             const __hip_bfloat16* __restrict__ wn,
                                             __hip_bfloat16* __restrict__ A,
                                             float4* __restrict__ params) {
  const int b = blockIdx.x;
  const int lane = threadIdx.x;
  const float4* er = (const float4*)(e + (size_t)b * D_SZ);
  float4 v0 = er[lane], v1 = er[64 + lane];
  float ss = v0.x*v0.x + v0.y*v0.y + v0.z*v0.z + v0.w*v0.w
           + v1.x*v1.x + v1.y*v1.y + v1.z*v1.z + v1.w*v1.w;
  #pragma unroll
  for (int o = 32; o; o >>= 1) ss += __shfl_xor(ss, o, 64);
  const float rn = __builtin_amdgcn_rsqf(fmaxf(ss, 1e-24f));
  v0.x *= rn; v0.y *= rn; v0.z *= rn; v0.w *= rn;
  v1.x *= rn; v1.y *= rn; v1.z *= rn; v1.w *= rn;

  ushort4 u0, u1;
  u0.x = bf16r(v0.x); u0.y = bf16r(v0.y); u0.z = bf16r(v0.z); u0.w = bf16r(v0.w);
  u1.x = bf16r(v1.x); u1.y = bf16r(v1.y); u1.z = bf16r(v1.z); u1.w = bf16r(v1.w);
  ushort4* arow_e = (ushort4*)(A + (size_t)(2 * b) * D_SZ);
  arow_e[lane] = u0;
  arow_e[64 + lane] = u1;

  const int lab = labels[b];
  const ushort4* wr = (const ushort4*)(wn + (size_t)lab * D_SZ);
  ushort4 w0 = wr[lane], w1 = wr[64 + lane];
  ushort4* arow_w = (ushort4*)(A + (size_t)(2 * b + 1) * D_SZ);
  arow_w[lane] = w0;
  arow_w[64 + lane] = w1;

  float d = v0.x*bf2f(w0.x) + v0.y*bf2f(w0.y) + v0.z*bf2f(w0.z) + v0.w*bf2f(w0.w)
          + v1.x*bf2f(w1.x) + v1.y*bf2f(w1.y) + v1.z*bf2f(w1.z) + v1.w*bf2f(w1.w);
  #pragma unroll
  for (int o = 32; o; o >>= 1) d += __shfl_xor(d, o, 64);

  if (lane == 0) {
    const float cos_m = 0.877582561890372716f;  // cos(0.5)
    const float sin_m = 0.479425538604203000f;  // sin(0.5)
    float cos_t = fminf(fmaxf(d, -1.0f), 1.0f);
    float sin_t = sqrtf(fmaxf(1.0f - cos_t * cos_t, 0.0f));
    float cos_tm = cos_t * cos_m - sin_t * sin_m;
    float sin_tm = sin_t * cos_m + cos_t * sin_m;
    float inv_st = 1.0f / fmaxf(sin_t, 1e-20f);
    params[b] = make_float4(cos_tm, sin_m * inv_st, sin_tm * inv_st, 0.0f);
  }
}

// ----- kernel 3: GEMM, double-buffered LDS, 2-phase pipeline + epilogue -----
__device__ __forceinline__ float termf(float de, float dwy, float4 p, bool kill) {
  float c = fminf(fmaxf(de, -1.0f), 1.0f);
  float s = p.z * dwy - p.y * de;            // (sin_tm*dwy - sin_m*de)/sin_t
  float x = fmaxf(fmaf(-2.0f, s, 2.0f), 1e-20f);
  float t = (c - p.x) * __builtin_amdgcn_rsqf(x);
  float r = __expf(t);
  return kill ? 0.0f : r;
}

__global__ __launch_bounds__(256) void k_gemm(const __hip_bfloat16* __restrict__ A,
                                              const __hip_bfloat16* __restrict__ Wn,
                                              const float4* __restrict__ params,
                                              const int* __restrict__ labels,
                                              float* __restrict__ part) {
  // Fragment-ordered LDS: [frag 0..7][kk 0..1][lane 0..63] x 16B chunks.
  __shared__ __align__(16) __hip_bfloat16 At[2][BM * BK];
  __shared__ __align__(16) __hip_bfloat16 Bt[2][BN * BK];
  __shared__ float ered[64];
  __shared__ float4 pl[64];
  __shared__ int ll[64];

  const int bid = blockIdx.x;
  const int p = (bid & 7) * NTILES + (bid >> 3);  // XCD-chunked remap
  const int nt = p >> 3, mt = p & 7;
  const int t = threadIdx.x;
  const int w = t >> 6, l = t & 63;
  const int m0 = mt * BM;
  const int n0 = nt * BN;
  const int b0 = mt * 64;

  if (t < 64) {
    ered[t] = 0.0f;
    pl[t] = params[b0 + t];
    ll[t] = labels[b0 + t];
  }

  // Fragment-order source offsets (elements) for staging.
  int aoff[4], boff[4];
  #pragma unroll
  for (int i = 0; i < 4; ++i) {
    int s = i * 256 + t;
    int lc = s & 63;
    int kki = (s >> 6) & 1;
    int fr = s >> 7;                 // fragment 0..7
    int row = fr * 16 + (lc & 15);
    int col = (kki * 4 + (lc >> 4)) * 8;
    aoff[i] = (m0 + row) * D_SZ + col;
    int j = n0 + row;
    if (j >= C_SZ) j = C_SZ - 1;     // clamp; masked in epilogue
    boff[i] = j * D_SZ + col;
  }

  f32x4 acc[4][4] = {};
  const int wm = (w >> 1) * 64;
  const int wn_ = (w & 1) * 64;
  const int r16 = l & 15;
  const int g = l >> 4;
  const int mfbase = (w >> 1) * 4;
  const int nfbase = (w & 1) * 4;

  // ---- prologue: stage tiles 0 and 1 ----
  #pragma unroll
  for (int i = 0; i < 4; ++i) {
    gload_lds16(A + aoff[i], (void*)(At[0] + (i * 256 + t) * 8));
    gload_lds16(Wn + (size_t)boff[i], (void*)(Bt[0] + (i * 256 + t) * 8));
  }
  #pragma unroll
  for (int i = 0; i < 4; ++i) {
    gload_lds16(A + aoff[i] + BK, (void*)(At[1] + (i * 256 + t) * 8));
    gload_lds16(Wn + (size_t)boff[i] + BK, (void*)(Bt[1] + (i * 256 + t) * 8));
  }
  __syncthreads();   // drain both prologue tiles; pl/ll/ered also ready

  // ---- main loop: compute(tile s from buf s&1); sync; stage(tile s+2) ----
  #pragma unroll
  for (int step = 0; step < KSTEPS; ++step) {
    const int cb = step & 1;
    #pragma unroll
    for (int kki = 0; kki < 2; ++kki) {
      bf16x8 af[4], bfr[4];
      #pragma unroll
      for (int mf = 0; mf < 4; ++mf)
        af[mf] = *(const bf16x8*)(At[cb] + (((mfbase + mf) * 2 + kki) * 64 + l) * 8);
      #pragma unroll
      for (int nf = 0; nf < 4; ++nf)
        bfr[nf] = *(const bf16x8*)(Bt[cb] + (((nfbase + nf) * 2 + kki) * 64 + l) * 8);
      #pragma unroll
      for (int mf = 0; mf < 4; ++mf)
        #pragma unroll
        for (int nf = 0; nf < 4; ++nf)
          acc[mf][nf] = __builtin_amdgcn_mfma_f32_16x16x32_bf16(
              af[mf], bfr[nf], acc[mf][nf], 0, 0, 0);
    }
    if (step < KSTEPS - 1) {
      __syncthreads();   // all waves done reading buf cb; tile step+1 loads drained
      if (step < KSTEPS - 2) {
        const int k0 = (step + 2) * BK;
        #pragma unroll
        for (int i = 0; i < 4; ++i) {
          gload_lds16(A + aoff[i] + k0, (void*)(At[cb] + (i * 256 + t) * 8));
          gload_lds16(Wn + (size_t)boff[i] + k0, (void*)(Bt[cb] + (i * 256 + t) * 8));
        }
      }
    }
  }

  // Epilogue: rows 2b (dot_e) and 2b+1 (dot_wy) are adjacent accumulator regs.
  #pragma unroll
  for (int mf = 0; mf < 4; ++mf) {
    int rloc = wm + mf * 16 + 4 * g;   // local A-row (even)
    int lb = rloc >> 1;                // local batch index (pair lb, lb+1)
    float4 p0 = pl[lb], p1 = pl[lb + 1];
    int lab0 = ll[lb], lab1 = ll[lb + 1];
    float s0 = 0.0f, s1 = 0.0f;
    #pragma unroll
    for (int nf = 0; nf < 4; ++nf) {
      int j = n0 + wn_ + nf * 16 + r16;
      bool oob = (j >= C_SZ);
      f32x4 c = acc[mf][nf];
      s0 += termf(c[0], c[1], p0, oob || (j == lab0));
      s1 += termf(c[2], c[3], p1, oob || (j == lab1));
    }
    // sum across the 16-lane r16 group (same lb), then one atomic
    #pragma unroll
    for (int o = 1; o < 16; o <<= 1) {
      s0 += __shfl_xor(s0, o, 64);
      s1 += __shfl_xor(s1, o, 64);
    }
    if (r16 == 0) {
      atomicAdd(&ered[lb], s0);
      atomicAdd(&ered[lb + 1], s1);
    }
  }
  __syncthreads();
  if (t < 64) part[(size_t)(b0 + t) * NTILES + nt] = ered[t];
}

// ---------------- kernel 4a: per-batch row sum + log1p ----------------
__global__ __launch_bounds__(256) void k_rowsum(const float* __restrict__ part,
                                                float* __restrict__ rowsum) {
  const int b = blockIdx.x;
  float s = 0.0f;
  for (int i = threadIdx.x; i < NTILES; i += 256) s += part[(size_t)b * NTILES + i];
  #pragma unroll
  for (int o = 32; o; o >>= 1) s += __shfl_xor(s, o, 64);
  __shared__ float red[4];
  if ((threadIdx.x & 63) == 0) red[threadIdx.x >> 6] = s;
  __syncthreads();
  if (threadIdx.x == 0)
    rowsum[b] = log1pf(red[0] + red[1] + red[2] + red[3]);
}

// ---------------- kernel 4b: final mean ----------------
__global__ __launch_bounds__(512) void k_final(const float* __restrict__ rowsum,
                                               float* __restrict__ out) {
  const int b = threadIdx.x;
  float v = rowsum[b];
  __shared__ float red[512];
  red[b] = v;
  __syncthreads();
  #pragma unroll
  for (int o = 256; o; o >>= 1) {
    if (b < o) red[b] += red[b + o];
    __syncthreads();
  }
  if (b == 0) out[0] = red[0] / (float)B_SZ;
}

extern "C" void kernel_launch(void* const* d_in, const int* in_sizes, int n_in,
                              void* d_out, int out_size, void* d_ws, size_t ws_size,
                              hipStream_t stream) {
  const float* emb = (const float*)d_in[0];
  const int* labels = (const int*)d_in[1];
  const float* w = (const float*)d_in[2];

  char* ws = (char*)d_ws;
  __hip_bfloat16* wn = (__hip_bfloat16*)ws;                       // 100000*512*2 B
  size_t off = (size_t)C_SZ * D_SZ * 2;
  __hip_bfloat16* Abuf = (__hip_bfloat16*)(ws + off);             // 1024*512*2 B
  off += (size_t)2 * B_SZ * D_SZ * 2;
  float4* params = (float4*)(ws + off);                           // 512*16 B
  off += (size_t)B_SZ * 16;
  float* part = (float*)(ws + off);                               // 512*782*4 B
  off += (size_t)B_SZ * NTILES * 4;
  float* rowsum = (float*)(ws + off);                             // 512*4 B
  off += (size_t)B_SZ * 4;

  k_norm_w<<<dim3(C_SZ / 4), dim3(256), 0, stream>>>(w, wn);
  k_prep<<<dim3(B_SZ), dim3(64), 0, stream>>>(emb, labels, wn, Abuf, params);
  k_gemm<<<dim3(NBLK), dim3(256), 0, stream>>>(Abuf, wn, params, labels, part);
  k_rowsum<<<dim3(B_SZ), dim3(256), 0, stream>>>(part, rowsum);
  k_final<<<dim3(1), dim3(512), 0, stream>>>(rowsum, (float*)d_out);
}

// Round 6
// 159.131 us; speedup vs baseline: 2.5823x; 1.6403x over previous
//
#include <hip/hip_runtime.h>
#include <hip/hip_fp8.h>
#include <math.h>

#define B_SZ 512
#define C_SZ 100000
#define D_SZ 512

#define BM 256
#define BN 128
#define BK 64
#define NTILES 782          // ceil(100000/128)
#define MT 4                // 1024 rows / BM
#define NBLK (NTILES * MT)  // 3128 (divisible by 8)
#define KSTEPS 8            // 512 / 64
#define DEPTH 3

typedef __attribute__((ext_vector_type(4))) float f32x4;
typedef __attribute__((ext_vector_type(2))) long lx2;

__device__ __forceinline__ void gload_lds16(const void* gptr, void* lptr) {
  __builtin_amdgcn_global_load_lds(
      (const __attribute__((address_space(1))) void*)gptr,
      (__attribute__((address_space(3))) void*)lptr,
      16, 0, 0);
}

__device__ __forceinline__ unsigned char f2fp8(float x) {
  __hip_fp8_e4m3 h(x);
  return (unsigned char)h.__x;
}
__device__ __forceinline__ float fp82f(unsigned int u) {
  __hip_fp8_e4m3 h;
  h.__x = (unsigned char)u;
  return (float)h;
}
__device__ __forceinline__ unsigned int pack4f8(float a, float b, float c, float d) {
  return (unsigned int)f2fp8(a) | ((unsigned int)f2fp8(b) << 8) |
         ((unsigned int)f2fp8(c) << 16) | ((unsigned int)f2fp8(d) << 24);
}

// ---------------- kernel 1: normalize weight rows -> fp8 ----------------
__global__ __launch_bounds__(256) void k_norm_w(const float* __restrict__ w,
                                                unsigned char* __restrict__ w8) {
  const int row = blockIdx.x * 4 + (threadIdx.x >> 6);
  const int lane = threadIdx.x & 63;
  const float4* wr = (const float4*)(w + (size_t)row * D_SZ);
  float4 v0 = wr[lane];
  float4 v1 = wr[64 + lane];
  float ss = v0.x*v0.x + v0.y*v0.y + v0.z*v0.z + v0.w*v0.w
           + v1.x*v1.x + v1.y*v1.y + v1.z*v1.z + v1.w*v1.w;
  #pragma unroll
  for (int o = 32; o; o >>= 1) ss += __shfl_xor(ss, o, 64);
  const float rn = __builtin_amdgcn_rsqf(fmaxf(ss, 1e-24f));
  unsigned int* out = (unsigned int*)(w8 + (size_t)row * D_SZ);
  out[lane] = pack4f8(v0.x * rn, v0.y * rn, v0.z * rn, v0.w * rn);
  out[64 + lane] = pack4f8(v1.x * rn, v1.y * rn, v1.z * rn, v1.w * rn);
}

// ------- kernel 2: normalize embeddings, gather w_y, per-row params -------
// A8 layout: row 2b = fp8(e_hat[b]), row 2b+1 = fp8 w_hat[label[b]] (bytes copied)
__global__ __launch_bounds__(64) void k_prep(const float* __restrict__ e,
                                             const int* __restrict__ labels,
                                             const unsigned char* __restrict__ w8,
                                             unsigned char* __restrict__ A8,
                                             float4* __restrict__ params) {
  const int b = blockIdx.x;
  const int lane = threadIdx.x;
  const float4* er = (const float4*)(e + (size_t)b * D_SZ);
  float4 v0 = er[lane], v1 = er[64 + lane];
  float ss = v0.x*v0.x + v0.y*v0.y + v0.z*v0.z + v0.w*v0.w
           + v1.x*v1.x + v1.y*v1.y + v1.z*v1.z + v1.w*v1.w;
  #pragma unroll
  for (int o = 32; o; o >>= 1) ss += __shfl_xor(ss, o, 64);
  const float rn = __builtin_amdgcn_rsqf(fmaxf(ss, 1e-24f));
  v0.x *= rn; v0.y *= rn; v0.z *= rn; v0.w *= rn;
  v1.x *= rn; v1.y *= rn; v1.z *= rn; v1.w *= rn;

  unsigned int* arow_e = (unsigned int*)(A8 + (size_t)(2 * b) * D_SZ);
  arow_e[lane] = pack4f8(v0.x, v0.y, v0.z, v0.w);
  arow_e[64 + lane] = pack4f8(v1.x, v1.y, v1.z, v1.w);

  const int lab = labels[b];
  const unsigned int* wr = (const unsigned int*)(w8 + (size_t)lab * D_SZ);
  unsigned int w0 = wr[lane], w1 = wr[64 + lane];
  unsigned int* arow_w = (unsigned int*)(A8 + (size_t)(2 * b + 1) * D_SZ);
  arow_w[lane] = w0;
  arow_w[64 + lane] = w1;

  float d = v0.x * fp82f(w0 & 255) + v0.y * fp82f((w0 >> 8) & 255)
          + v0.z * fp82f((w0 >> 16) & 255) + v0.w * fp82f(w0 >> 24)
          + v1.x * fp82f(w1 & 255) + v1.y * fp82f((w1 >> 8) & 255)
          + v1.z * fp82f((w1 >> 16) & 255) + v1.w * fp82f(w1 >> 24);
  #pragma unroll
  for (int o = 32; o; o >>= 1) d += __shfl_xor(d, o, 64);

  if (lane == 0) {
    const float cos_m = 0.877582561890372716f;  // cos(0.5)
    const float sin_m = 0.479425538604203000f;  // sin(0.5)
    float cos_t = fminf(fmaxf(d, -1.0f), 1.0f);
    float sin_t = sqrtf(fmaxf(1.0f - cos_t * cos_t, 0.0f));
    float cos_tm = cos_t * cos_m - sin_t * sin_m;
    float sin_tm = sin_t * cos_m + cos_t * sin_m;
    float inv_st = 1.0f / fmaxf(sin_t, 1e-20f);
    params[b] = make_float4(cos_tm, sin_m * inv_st, sin_tm * inv_st, 0.0f);
  }
}

// ---- kernel 3: fp8 GEMM, depth-3 counted-vmcnt pipeline + fused epilogue ----
__device__ __forceinline__ float termf(float de, float dwy, float4 p, bool kill) {
  float c = fminf(fmaxf(de, -1.0f), 1.0f);
  float s = p.z * dwy - p.y * de;            // (sin_tm*dwy - sin_m*de)/sin_t
  float x = fmaxf(fmaf(-2.0f, s, 2.0f), 1e-20f);
  float t = (c - p.x) * __builtin_amdgcn_rsqf(x);
  float r = __expf(t);
  return kill ? 0.0f : r;
}

__global__ __launch_bounds__(512, 4) void k_gemm(const unsigned char* __restrict__ A8,
                                                 const unsigned char* __restrict__ W8,
                                                 const float4* __restrict__ params,
                                                 const int* __restrict__ labels,
                                                 float* __restrict__ part) {
  // Fragment-pair-ordered fp8 LDS: slot = frag*64 + lane, 16 B per slot
  // (16 contiguous source-k bytes; permuted-K split 8+8 across two MFMAs).
  __shared__ __align__(16) unsigned char At[DEPTH][BM * BK];   // 3 x 16 KB
  __shared__ __align__(16) unsigned char Bt[DEPTH][BN * BK];   // 3 x 8 KB
  __shared__ float ered[128];
  __shared__ float4 pl[128];
  __shared__ int ll[128];

  const int bid = blockIdx.x;
  const int p = (bid & 7) * (NBLK / 8) + (bid >> 3);  // XCD-chunked remap
  const int nt = p >> 2, mt = p & 3;                  // mt fastest within XCD
  const int t = threadIdx.x;
  const int w = t >> 6, l = t & 63;
  const int m0 = mt * BM;
  const int n0 = nt * BN;
  const int b0 = mt * (BM / 2);

  if (t < 128) {
    ered[t] = 0.0f;
    pl[t] = params[b0 + t];
    ll[t] = labels[b0 + t];
  }

  // Staging source offsets (fp8 bytes). Thread t stages:
  //  A slots t and 512+t; B slot t.  slot = frag*64 + lc; lane lc holds
  //  row (frag*16 + (lc&15)), source k-bytes [(lc>>4)*16, +16).
  const int lcA = t & 63;
  const int faA = t >> 6;
  const int aoff0 = (m0 + faA * 16 + (lcA & 15)) * D_SZ + (lcA >> 4) * 16;
  const int aoff1 = (m0 + (8 + faA) * 16 + (lcA & 15)) * D_SZ + (lcA >> 4) * 16;
  int brow = n0 + faA * 16 + (lcA & 15);
  if (brow >= C_SZ) brow = C_SZ - 1;   // clamp; masked in epilogue
  const int boff = brow * D_SZ + (lcA >> 4) * 16;

  f32x4 acc[4][4] = {};
  const int wm = (w >> 1) * 64;        // wave m-origin (of 256)
  const int wn_ = (w & 1) * 64;        // wave n-origin (of 128)
  const int r16 = l & 15;
  const int g = l >> 4;
  const int mfbase = (w >> 1) * 4;
  const int nfbase = (w & 1) * 4;

#define STAGE(d, ts)                                                        \
  do {                                                                      \
    const int k0_ = (ts) * BK;                                              \
    gload_lds16(A8 + aoff0 + k0_, (void*)(At[d] + t * 16));                 \
    gload_lds16(A8 + aoff1 + k0_, (void*)(At[d] + (512 + t) * 16));         \
    gload_lds16(W8 + (size_t)(boff + k0_), (void*)(Bt[d] + t * 16));        \
  } while (0)

  // ---- prologue: stage tiles 0,1,2 ----
  STAGE(0, 0);
  STAGE(1, 1);
  STAGE(2, 2);
  asm volatile("s_waitcnt vmcnt(6) lgkmcnt(0)" ::: "memory");  // tile 0 landed
  __builtin_amdgcn_s_barrier();

  // ---- main loop: one raw barrier per step, vmcnt never drained to 0 ----
  #pragma unroll
  for (int step = 0; step < KSTEPS; ++step) {
    const int d = step % DEPTH;
    lx2 ap[4], bp[4];
    #pragma unroll
    for (int mf = 0; mf < 4; ++mf)
      ap[mf] = *(const lx2*)(At[d] + ((mfbase + mf) * 64 + l) * 16);
    #pragma unroll
    for (int nf = 0; nf < 4; ++nf)
      bp[nf] = *(const lx2*)(Bt[d] + ((nfbase + nf) * 64 + l) * 16);
    #pragma unroll
    for (int mf = 0; mf < 4; ++mf)
      #pragma unroll
      for (int nf = 0; nf < 4; ++nf) {
        acc[mf][nf] = __builtin_amdgcn_mfma_f32_16x16x32_fp8_fp8(
            ap[mf][0], bp[nf][0], acc[mf][nf], 0, 0, 0);
        acc[mf][nf] = __builtin_amdgcn_mfma_f32_16x16x32_fp8_fp8(
            ap[mf][1], bp[nf][1], acc[mf][nf], 0, 0, 0);
      }
    if (step < KSTEPS - 1) {
      // newest 3 vmem = the stage issued last iteration; tiles <= step+1 landed
      asm volatile("s_waitcnt vmcnt(3)" ::: "memory");
      __builtin_amdgcn_s_barrier();
      if (step + DEPTH < KSTEPS)
        STAGE(d, step + DEPTH);
    }
  }
#undef STAGE

  // Epilogue: rows 2b (dot_e) and 2b+1 (dot_wy) are adjacent accumulator regs.
  #pragma unroll
  for (int mf = 0; mf < 4; ++mf) {
    int lb = (wm >> 1) + mf * 8 + 2 * g;   // local batch index (pair lb, lb+1)
    float4 p0 = pl[lb], p1 = pl[lb + 1];
    int lab0 = ll[lb], lab1 = ll[lb + 1];
    float s0 = 0.0f, s1 = 0.0f;
    #pragma unroll
    for (int nf = 0; nf < 4; ++nf) {
      int j = n0 + wn_ + nf * 16 + r16;
      bool oob = (j >= C_SZ);
      f32x4 c = acc[mf][nf];
      s0 += termf(c[0], c[1], p0, oob || (j == lab0));
      s1 += termf(c[2], c[3], p1, oob || (j == lab1));
    }
    #pragma unroll
    for (int o = 1; o < 16; o <<= 1) {
      s0 += __shfl_xor(s0, o, 64);
      s1 += __shfl_xor(s1, o, 64);
    }
    if (r16 == 0) {
      atomicAdd(&ered[lb], s0);
      atomicAdd(&ered[lb + 1], s1);
    }
  }
  __syncthreads();
  if (t < 128) part[(size_t)(b0 + t) * NTILES + nt] = ered[t];
}

// ---------------- kernel 4a: per-batch row sum + log1p ----------------
__global__ __launch_bounds__(256) void k_rowsum(const float* __restrict__ part,
                                                float* __restrict__ rowsum) {
  const int b = blockIdx.x;
  float s = 0.0f;
  for (int i = threadIdx.x; i < NTILES; i += 256) s += part[(size_t)b * NTILES + i];
  #pragma unroll
  for (int o = 32; o; o >>= 1) s += __shfl_xor(s, o, 64);
  __shared__ float red[4];
  if ((threadIdx.x & 63) == 0) red[threadIdx.x >> 6] = s;
  __syncthreads();
  if (threadIdx.x == 0)
    rowsum[b] = log1pf(red[0] + red[1] + red[2] + red[3]);
}

// ---------------- kernel 4b: final mean ----------------
__global__ __launch_bounds__(512) void k_final(const float* __restrict__ rowsum,
                                               float* __restrict__ out) {
  const int b = threadIdx.x;
  float v = rowsum[b];
  __shared__ float red[512];
  red[b] = v;
  __syncthreads();
  #pragma unroll
  for (int o = 256; o; o >>= 1) {
    if (b < o) red[b] += red[b + o];
    __syncthreads();
  }
  if (b == 0) out[0] = red[0] / (float)B_SZ;
}

extern "C" void kernel_launch(void* const* d_in, const int* in_sizes, int n_in,
                              void* d_out, int out_size, void* d_ws, size_t ws_size,
                              hipStream_t stream) {
  const float* emb = (const float*)d_in[0];
  const int* labels = (const int*)d_in[1];
  const float* w = (const float*)d_in[2];

  char* ws = (char*)d_ws;
  unsigned char* w8 = (unsigned char*)ws;                  // 100000*512 B
  size_t off = (size_t)C_SZ * D_SZ;
  unsigned char* A8 = (unsigned char*)(ws + off);          // 1024*512 B
  off += (size_t)2 * B_SZ * D_SZ;
  float4* params = (float4*)(ws + off);                    // 512*16 B
  off += (size_t)B_SZ * 16;
  float* part = (float*)(ws + off);                        // 512*782*4 B
  off += (size_t)B_SZ * NTILES * 4;
  float* rowsum = (float*)(ws + off);                      // 512*4 B
  off += (size_t)B_SZ * 4;

  k_norm_w<<<dim3(C_SZ / 4), dim3(256), 0, stream>>>(w, w8);
  k_prep<<<dim3(B_SZ), dim3(64), 0, stream>>>(emb, labels, w8, A8, params);
  k_gemm<<<dim3(NBLK), dim3(512), 0, stream>>>(A8, w8, params, labels, part);
  k_rowsum<<<dim3(B_SZ), dim3(256), 0, stream>>>(part, rowsum);
  k_final<<<dim3(1), dim3(512), 0, stream>>>(rowsum, (float*)d_out);
}